// Round 1
// baseline (93.839 us; speedup 1.0000x reference)
//
#include <hip/hip_runtime.h>
#include <hip/hip_cooperative_groups.h>
#include <math.h>

namespace cg = cooperative_groups;

#define N_BINS 256
#define TAU 0.01f
#define EPS 1e-10f
#define HW (512*512)
#define Q 4081            // quant levels; Q-1 = 4080 = 16*255 so t_q - b_j = (q-16j)/4080
#define QSTRIDE 4096
#define MWIN 208          // |q-16j| <= 208 -> dropped weight exp(-13) ~ 2e-6 (negligible)
#define WTAB (2*MWIN+1)   // 417
#define WPADN 432         // 16*27, zero-padded tail
#define NP 27             // taps per phase: m = 16*(p-13)+r
#define CFP_STRIDE 289    // odd stride -> 2-way bank aliasing only (free)
#define NPART 64          // partial soft-hists per batch
#define REDS 260          // red row stride (floats); 260*4 bytes is 16B-aligned

// Fused: fine hist -> conv -> partial store -> GRID SYNC -> reduce -> scan -> LUT -> equalize.
// One dispatch instead of two: saves a launch boundary, the 4 MiB x re-read (pixels held in
// registers across the sync), and the duplicated wtE/LDS setup. 256 blocks = 1/CU, 8 waves,
// 37.6 KB LDS -> co-residency trivially satisfied for cooperative launch.
__global__ __launch_bounds__(512) void fused_equalize_kernel(const float* __restrict__ x,
                                                             float* __restrict__ partT,
                                                             float* __restrict__ out) {
    // Phase-overlaid LDS. A: conv input (phase 1) / output LUT (phase 3).
    // Bu: fine hist + phase-hist (phase 1) / reduce+scan scratch (phase 2).
    __shared__ union {
        float cfp[16 * CFP_STRIDE];      // 18.5 KB
        float Tl[QSTRIDE];               // 16 KB
    } A;
    __shared__ union {
        unsigned int lh[QSTRIDE];        // 16 KB
        float ph[256 * 17];              // 17.4 KB
        struct {
            __align__(16) float red[8 * REDS];   // 8.3 KB
            float cdfnp[288];
            float onesp[288];
            float wsum[4];
            float h0s;
        } p2;
    } Bu;
    __shared__ float wtE[WPADN];

    const int b    = blockIdx.y;
    const int s    = blockIdx.x;
    const int tid  = threadIdx.x;
    const int r    = tid & 15;
    const int t    = tid >> 4;       // 0..31
    const int wv   = tid >> 6;       // wave 0..7
    const int lane = tid & 63;

    for (int i = tid; i < QSTRIDE; i += 512) Bu.lh[i] = 0u;
    for (int i = tid; i < 16 * CFP_STRIDE; i += 512) A.cfp[i] = 0.f;
    for (int i = tid; i < WPADN; i += 512) {
        const float d = (float)(i - MWIN) * (1.0f / 4080.f);
        wtE[i] = (i < WTAB) ? __expf(-d * d * (1.0f / (2.0f * TAU * TAU))) : 0.f;
    }

    // pixel loads issued before the barrier; held in registers for the whole kernel
    const float4* xb = (const float4*)(x + (size_t)b * HW + (size_t)s * 4096);
    float4 px[2];
    px[0] = xb[tid];
    px[1] = xb[512 + tid];
    __syncthreads();

    // ---- phase 1a: fine histogram (LDS atomics, ~1 count/bin expected) ----
#pragma unroll
    for (int i = 0; i < 2; ++i) {
        const float4 v = px[i];
        int q0 = __float2int_rn(v.x * 4080.f);
        int q1 = __float2int_rn(v.y * 4080.f);
        int q2 = __float2int_rn(v.z * 4080.f);
        int q3 = __float2int_rn(v.w * 4080.f);
        q0 = min(max(q0, 0), Q - 1); q1 = min(max(q1, 0), Q - 1);
        q2 = min(max(q2, 0), Q - 1); q3 = min(max(q3, 0), Q - 1);
        atomicAdd(&Bu.lh[q0], 1u); atomicAdd(&Bu.lh[q1], 1u);
        atomicAdd(&Bu.lh[q2], 1u); atomicAdd(&Bu.lh[q3], 1u);
    }
    __syncthreads();

    // scatter fine hist phase-transposed into cfp (pads stay zero)
#pragma unroll
    for (int k = 0; k < 8; ++k) {
        const int q = k * 512 + tid;
        A.cfp[(q & 15) * CFP_STRIDE + (q >> 4) + 13] = (float)Bu.lh[q];
    }
    __syncthreads();

    // ---- phase 1b: register-blocked conv; thread (r,t) computes bins 8t..8t+7, phase r ----
    {
        float creg[34];
        const float* cbase = &A.cfp[r * CFP_STRIDE + 8 * t];
#pragma unroll
        for (int k = 0; k < 34; ++k) creg[k] = cbase[k];
        float acc[8];
#pragma unroll
        for (int uu = 0; uu < 8; ++uu) acc[uu] = 0.f;
#pragma unroll
        for (int p = 0; p < NP; ++p) {
            const float w = wtE[16 * p + r];
#pragma unroll
            for (int uu = 0; uu < 8; ++uu) acc[uu] += w * creg[uu + p];
        }
#pragma unroll
        for (int uu = 0; uu < 8; ++uu) Bu.ph[(8 * t + uu) * 17 + r] = acc[uu];
    }
    __syncthreads();

    // phase-reduce -> coalesced store of this block's partial soft-hist
    if (tid < N_BINS) {
        float hv = 0.f;
#pragma unroll
        for (int rr = 0; rr < 16; ++rr) hv += Bu.ph[tid * 17 + rr];
        partT[((size_t)b * NPART + s) * N_BINS + tid] = hv;
    }

    // ---- device-wide barrier: all partials visible to all blocks ----
    cg::this_grid().sync();

    // ---- phase 2: reduce 64x256 partials (p2 overlays ph; safe after grid sync) ----
    for (int i = tid; i < 288; i += 512) {
        Bu.p2.cdfnp[i] = 0.f;
        Bu.p2.onesp[i] = (i >= 13 && i < 269) ? 1.f : 0.f;
    }
    {
        const float4* base4 = (const float4*)(partT + (size_t)b * NPART * N_BINS);
        float4 a4 = make_float4(0.f, 0.f, 0.f, 0.f);
#pragma unroll
        for (int rr = 0; rr < 8; ++rr) {
            const float4 v = base4[(size_t)(8 * wv + rr) * 64 + lane];
            a4.x += v.x; a4.y += v.y; a4.z += v.z; a4.w += v.w;
        }
        ((float4*)&Bu.p2.red[wv * REDS])[lane] = a4;
    }
    __syncthreads();

    // cross-wave reduce + wave-shuffle scan over 256 bins + cdf normalization
    float val = 0.f, hv = 0.f;
    if (tid < N_BINS) {
#pragma unroll
        for (int w2 = 0; w2 < 8; ++w2) hv += Bu.p2.red[w2 * REDS + tid];
        val = hv;
#pragma unroll
        for (int d = 1; d < 64; d <<= 1) {
            const float n = __shfl_up(val, (unsigned)d, 64);
            if (lane >= d) val += n;
        }
        if (lane == 63) Bu.p2.wsum[tid >> 6] = val;
        if (tid == 0) Bu.p2.h0s = hv;
    }
    __syncthreads();
    if (tid < N_BINS) {
        float prefix = 0.f, total = 0.f;
#pragma unroll
        for (int w2 = 0; w2 < 4; ++w2) {
            const float ws = Bu.p2.wsum[w2];
            if (w2 < (tid >> 6)) prefix += ws;
            total += ws;
        }
        val += prefix;
        const float inv  = 1.0f / (total + EPS);
        const float cdf0 = Bu.p2.h0s * inv;
        Bu.p2.cdfnp[tid + 13] = (val * inv - cdf0) / (1.0f - cdf0 + EPS);
    }
    __syncthreads();

    // ---- phase 3: output LUT (Tl overlays cfp; cfp dead since phase 1b) ----
    {
        float creg[34], oreg[34];
        const int base = 8 * t;
#pragma unroll
        for (int k = 0; k < 34; ++k) { creg[k] = Bu.p2.cdfnp[base + k]; oreg[k] = Bu.p2.onesp[base + k]; }
        float acc[8], sw[8];
#pragma unroll
        for (int uu = 0; uu < 8; ++uu) { acc[uu] = 0.f; sw[uu] = 0.f; }
#pragma unroll
        for (int p = 0; p < NP; ++p) {
            const float w = wtE[16 * p + r];
#pragma unroll
            for (int uu = 0; uu < 8; ++uu) {
                const int k = uu - p + 26;   // in [0,34)
                acc[uu] += w * creg[k];
                sw[uu]  += w * oreg[k];
            }
        }
#pragma unroll
        for (int uu = 0; uu < 8; ++uu)
            A.Tl[16 * (8 * t + uu) + r] = acc[uu] / (sw[uu] + EPS);
    }
    __syncthreads();

    // ---- equalize register-held pixels via LUT lerp ----
    float4* ob = (float4*)(out + (size_t)b * HW + (size_t)s * 4096);
#pragma unroll
    for (int i = 0; i < 2; ++i) {
        const float4 v = px[i];
        const float vv[4] = {v.x, v.y, v.z, v.w};
        float res[4];
#pragma unroll
        for (int k2 = 0; k2 < 4; ++k2) {
            const float u = vv[k2] * 4080.f;
            int q = (int)u;
            q = min(max(q, 0), Q - 2);
            const float frac = u - (float)q;
            const float t0 = A.Tl[q], t1 = A.Tl[q + 1];
            res[k2] = fmaf(frac, t1 - t0, t0);
        }
        ob[i * 512 + tid] = make_float4(res[0], res[1], res[2], res[3]);
    }
}

extern "C" void kernel_launch(void* const* d_in, const int* in_sizes, int n_in,
                              void* d_out, int out_size, void* d_ws, size_t ws_size,
                              hipStream_t stream) {
    const float* x = (const float*)d_in[0];
    float* out     = (float*)d_out;
    const int B    = in_sizes[0] / HW;   // = 4

    float* partT = (float*)d_ws;         // B*64*256 floats = 256 KB, plain stores (no memset)

    void* args[] = { (void*)&x, (void*)&partT, (void*)&out };
    hipLaunchCooperativeKernel((const void*)fused_equalize_kernel,
                               dim3(NPART, B), dim3(512), args, 0, stream);
}

// Round 2
// 83.583 us; speedup vs baseline: 1.1227x; 1.1227x over previous
//
#include <hip/hip_runtime.h>
#include <math.h>

#define N_BINS 256
#define TAU 0.01f
#define EPS 1e-10f
#define HW (512*512)
#define Q 4081            // quant levels; Q-1 = 4080 = 16*255 so t_q - b_j = (q-16j)/4080
#define QSTRIDE 4096
#define MWIN 208          // |q-16j| <= 208 -> dropped weight exp(-13) ~ 2e-6 (negligible)
#define WTAB (2*MWIN+1)   // 417
#define WPADN 432         // 16*27, zero-padded tail
#define NP 27             // taps per phase: m = 16*(p-13)+r
#define CFP_STRIDE 289    // odd stride -> 2-way bank aliasing only (free)
#define NPART 64          // partial soft-hists per batch
#define REDS 260          // red row stride (floats); 260*4 bytes is 16B-aligned

// --- grid barrier state: generation counter => no per-iteration reset, graph-replay safe.
// Separate cache lines so 255 spinners on g_gen don't contend with arrivals on g_count.
__device__ __align__(256) unsigned int g_count = 0u;
__device__ __align__(256) unsigned int g_gen   = 0u;

// Fused: fine hist -> conv -> partial store -> custom grid barrier -> reduce -> scan ->
// LUT -> equalize. Regular launch (graph-capturable, unlike hipLaunchCooperativeKernel,
// which cost +32us in round 1). Co-residency is capacity-guaranteed: 256 blocks, each CU
// holds up to 4 (8 waves, ~40KB LDS), so all blocks are dispatched before any spin.
__global__ __launch_bounds__(512) void fused_equalize_kernel(const float* __restrict__ x,
                                                             float* __restrict__ partT,
                                                             float* __restrict__ out,
                                                             int nblk) {
    // Phase-overlaid LDS. A: conv input (phase 1) / output LUT (phase 3).
    // Bu: fine hist + phase-hist (phase 1) / reduce scratch (phase 2).
    __shared__ union {
        float cfp[16 * CFP_STRIDE];      // 18.5 KB
        float Tl[QSTRIDE];               // 16 KB
    } A;
    __shared__ union {
        unsigned int lh[QSTRIDE];        // 16 KB
        float ph[256 * 17];              // 17.4 KB
        struct {
            __align__(16) float red[8 * REDS];   // 8.3 KB
            float wsum[4];
            float h0s;
        } p2;
    } Bu;
    __shared__ float wtE[WPADN];
    __shared__ float cdfnp[288];         // out of the union: init pre-barrier
    __shared__ float onesp[288];

    const int b    = blockIdx.y;
    const int s    = blockIdx.x;
    const int tid  = threadIdx.x;
    const int r    = tid & 15;
    const int t    = tid >> 4;       // 0..31
    const int wv   = tid >> 6;       // wave 0..7
    const int lane = tid & 63;

    for (int i = tid; i < QSTRIDE; i += 512) Bu.lh[i] = 0u;
    for (int i = tid; i < 16 * CFP_STRIDE; i += 512) A.cfp[i] = 0.f;
    for (int i = tid; i < WPADN; i += 512) {
        const float d = (float)(i - MWIN) * (1.0f / 4080.f);
        wtE[i] = (i < WTAB) ? __expf(-d * d * (1.0f / (2.0f * TAU * TAU))) : 0.f;
    }
    for (int i = tid; i < 288; i += 512) {
        cdfnp[i] = 0.f;
        onesp[i] = (i >= 13 && i < 269) ? 1.f : 0.f;
    }

    // pixel loads issued before the barrier; held in registers for the whole kernel
    const float4* xb = (const float4*)(x + (size_t)b * HW + (size_t)s * 4096);
    float4 px[2];
    px[0] = xb[tid];
    px[1] = xb[512 + tid];
    __syncthreads();

    // ---- phase 1a: fine histogram (LDS atomics, ~1 count/bin expected) ----
#pragma unroll
    for (int i = 0; i < 2; ++i) {
        const float4 v = px[i];
        int q0 = __float2int_rn(v.x * 4080.f);
        int q1 = __float2int_rn(v.y * 4080.f);
        int q2 = __float2int_rn(v.z * 4080.f);
        int q3 = __float2int_rn(v.w * 4080.f);
        q0 = min(max(q0, 0), Q - 1); q1 = min(max(q1, 0), Q - 1);
        q2 = min(max(q2, 0), Q - 1); q3 = min(max(q3, 0), Q - 1);
        atomicAdd(&Bu.lh[q0], 1u); atomicAdd(&Bu.lh[q1], 1u);
        atomicAdd(&Bu.lh[q2], 1u); atomicAdd(&Bu.lh[q3], 1u);
    }
    __syncthreads();

    // scatter fine hist phase-transposed into cfp (pads stay zero)
#pragma unroll
    for (int k = 0; k < 8; ++k) {
        const int q = k * 512 + tid;
        A.cfp[(q & 15) * CFP_STRIDE + (q >> 4) + 13] = (float)Bu.lh[q];
    }
    __syncthreads();

    // ---- phase 1b: register-blocked conv; thread (r,t) computes bins 8t..8t+7, phase r ----
    {
        float creg[34];
        const float* cbase = &A.cfp[r * CFP_STRIDE + 8 * t];
#pragma unroll
        for (int k = 0; k < 34; ++k) creg[k] = cbase[k];
        float acc[8];
#pragma unroll
        for (int uu = 0; uu < 8; ++uu) acc[uu] = 0.f;
#pragma unroll
        for (int p = 0; p < NP; ++p) {
            const float w = wtE[16 * p + r];
#pragma unroll
            for (int uu = 0; uu < 8; ++uu) acc[uu] += w * creg[uu + p];
        }
#pragma unroll
        for (int uu = 0; uu < 8; ++uu) Bu.ph[(8 * t + uu) * 17 + r] = acc[uu];
    }
    __syncthreads();

    // phase-reduce -> coalesced store of this block's partial soft-hist
    if (tid < N_BINS) {
        float hv = 0.f;
#pragma unroll
        for (int rr = 0; rr < 16; ++rr) hv += Bu.ph[tid * 17 + rr];
        partT[((size_t)b * NPART + s) * N_BINS + tid] = hv;
    }

    // ---- device-wide barrier: generation counter + agent-scope fences ----
    __syncthreads();
    if (tid == 0) {
        __threadfence();   // partT stores visible device-wide before signaling
        const unsigned int my = __hip_atomic_load(&g_gen, __ATOMIC_RELAXED,
                                                  __HIP_MEMORY_SCOPE_AGENT);
        const unsigned int prev = __hip_atomic_fetch_add(&g_count, 1u, __ATOMIC_ACQ_REL,
                                                         __HIP_MEMORY_SCOPE_AGENT);
        if (prev == (unsigned int)(nblk - 1)) {
            __hip_atomic_store(&g_count, 0u, __ATOMIC_RELAXED, __HIP_MEMORY_SCOPE_AGENT);
            __hip_atomic_fetch_add(&g_gen, 1u, __ATOMIC_RELEASE, __HIP_MEMORY_SCOPE_AGENT);
        } else {
            while (__hip_atomic_load(&g_gen, __ATOMIC_ACQUIRE,
                                     __HIP_MEMORY_SCOPE_AGENT) == my) {
                __builtin_amdgcn_s_sleep(1);
            }
        }
        __threadfence();   // acquire: other XCDs' partT stores visible to this block
    }
    __syncthreads();

    // ---- phase 2: reduce 64x256 partials (p2 overlays ph; dead since partial-store) ----
    {
        const float4* base4 = (const float4*)(partT + (size_t)b * NPART * N_BINS);
        float4 a4 = make_float4(0.f, 0.f, 0.f, 0.f);
#pragma unroll
        for (int rr = 0; rr < 8; ++rr) {
            const float4 v = base4[(size_t)(8 * wv + rr) * 64 + lane];
            a4.x += v.x; a4.y += v.y; a4.z += v.z; a4.w += v.w;
        }
        ((float4*)&Bu.p2.red[wv * REDS])[lane] = a4;
    }
    __syncthreads();

    // cross-wave reduce + wave-shuffle scan over 256 bins + cdf normalization
    float val = 0.f, hv = 0.f;
    if (tid < N_BINS) {
#pragma unroll
        for (int w2 = 0; w2 < 8; ++w2) hv += Bu.p2.red[w2 * REDS + tid];
        val = hv;
#pragma unroll
        for (int d = 1; d < 64; d <<= 1) {
            const float n = __shfl_up(val, (unsigned)d, 64);
            if (lane >= d) val += n;
        }
        if (lane == 63) Bu.p2.wsum[tid >> 6] = val;
        if (tid == 0) Bu.p2.h0s = hv;
    }
    __syncthreads();
    if (tid < N_BINS) {
        float prefix = 0.f, total = 0.f;
#pragma unroll
        for (int w2 = 0; w2 < 4; ++w2) {
            const float ws = Bu.p2.wsum[w2];
            if (w2 < (tid >> 6)) prefix += ws;
            total += ws;
        }
        val += prefix;
        const float inv  = 1.0f / (total + EPS);
        const float cdf0 = Bu.p2.h0s * inv;
        cdfnp[tid + 13] = (val * inv - cdf0) / (1.0f - cdf0 + EPS);
    }
    __syncthreads();

    // ---- phase 3: output LUT (Tl overlays cfp; cfp dead since phase 1b) ----
    {
        float creg[34], oreg[34];
        const int base = 8 * t;
#pragma unroll
        for (int k = 0; k < 34; ++k) { creg[k] = cdfnp[base + k]; oreg[k] = onesp[base + k]; }
        float acc[8], sw[8];
#pragma unroll
        for (int uu = 0; uu < 8; ++uu) { acc[uu] = 0.f; sw[uu] = 0.f; }
#pragma unroll
        for (int p = 0; p < NP; ++p) {
            const float w = wtE[16 * p + r];
#pragma unroll
            for (int uu = 0; uu < 8; ++uu) {
                const int k = uu - p + 26;   // in [0,34)
                acc[uu] += w * creg[k];
                sw[uu]  += w * oreg[k];
            }
        }
#pragma unroll
        for (int uu = 0; uu < 8; ++uu)
            A.Tl[16 * (8 * t + uu) + r] = acc[uu] / (sw[uu] + EPS);
    }
    __syncthreads();

    // ---- equalize register-held pixels via LUT lerp ----
    float4* ob = (float4*)(out + (size_t)b * HW + (size_t)s * 4096);
#pragma unroll
    for (int i = 0; i < 2; ++i) {
        const float4 v = px[i];
        const float vv[4] = {v.x, v.y, v.z, v.w};
        float res[4];
#pragma unroll
        for (int k2 = 0; k2 < 4; ++k2) {
            const float u = vv[k2] * 4080.f;
            int q = (int)u;
            q = min(max(q, 0), Q - 2);
            const float frac = u - (float)q;
            const float t0 = A.Tl[q], t1 = A.Tl[q + 1];
            res[k2] = fmaf(frac, t1 - t0, t0);
        }
        ob[i * 512 + tid] = make_float4(res[0], res[1], res[2], res[3]);
    }
}

extern "C" void kernel_launch(void* const* d_in, const int* in_sizes, int n_in,
                              void* d_out, int out_size, void* d_ws, size_t ws_size,
                              hipStream_t stream) {
    const float* x = (const float*)d_in[0];
    float* out     = (float*)d_out;
    const int B    = in_sizes[0] / HW;   // = 4

    float* partT = (float*)d_ws;         // B*64*256 floats = 256 KB, plain stores (no memset)

    fused_equalize_kernel<<<dim3(NPART, B), 512, 0, stream>>>(x, partT, out, NPART * B);
}

// Round 3
// 63.851 us; speedup vs baseline: 1.4697x; 1.3090x over previous
//
#include <hip/hip_runtime.h>
#include <math.h>

#define N_BINS 256
#define TAU 0.01f
#define EPS 1e-10f
#define HW (512*512)
#define Q 4081            // quant levels; Q-1 = 4080 = 16*255 so t_q - b_j = (q-16j)/4080
#define QSTRIDE 4096
#define MWIN 208          // |q-16j| <= 208 -> dropped weight exp(-13) ~ 2e-6 (negligible)
#define WTAB (2*MWIN+1)   // 417
#define WPADN 432         // 16*27, zero-padded tail
#define NP 27             // taps per phase: m = 16*(p-13)+r
#define CFP_STRIDE 289    // odd stride -> 2-way bank aliasing only (free)
#define NPART 64          // partial soft-hists per batch
#define BMAX 4

// ---- barrier + partial state in __device__ globals (d_ws untouched entirely).
// Hierarchical arrival: 32 L1 counters (8 arrivals each, own 64B line) -> 1 L2 counter
// (32 arrivals) -> g_gen bump. Longest serialized RMW chain ~40 instead of 256.
// All counters return to 0 every execution (last-arriver resets) -> graph-replay safe.
__device__ __align__(64) unsigned int g_l1[32 * 16];   // counter i at g_l1[i*16]
__device__ __align__(64) unsigned int g_l2v = 0u;
__device__ __align__(64) unsigned int g_gen = 0u;
__device__ __align__(16) float g_partT[BMAX * NPART * N_BINS];   // 256 KB

// Fused: fine hist -> conv -> partial store (write-through atomics) -> hierarchical
// grid barrier (relaxed RMWs, no threadfence/wbl2) -> reduce -> scan -> LUT -> equalize.
// Regular launch => graph-capturable. Co-residency capacity-guaranteed: 256 blocks,
// each CU holds 4 (8 waves, ~40KB LDS), so all blocks are resident before any spin.
__global__ __launch_bounds__(512) void fused_equalize_kernel(const float* __restrict__ x,
                                                             float* __restrict__ out,
                                                             int nblk, int ngrp) {
    // Phase-overlaid LDS. A: conv input (phase 1) / output LUT (phase 3).
    // Bu: fine hist + phase-hist (phase 1) / reduce scratch (phase 2).
    __shared__ union {
        float cfp[16 * CFP_STRIDE];      // 18.5 KB
        float Tl[QSTRIDE];               // 16 KB
    } A;
    __shared__ union {
        unsigned int lh[QSTRIDE];        // 16 KB
        float ph[256 * 17];              // 17.4 KB
        struct {
            float red2[512];
            float wsum[4];
            float h0s;
        } p2;
    } Bu;
    __shared__ float wtE[WPADN];
    __shared__ float cdfnp[288];
    __shared__ float onesp[288];

    const int b    = blockIdx.y;
    const int s    = blockIdx.x;
    const int bid  = b * NPART + s;
    const int tid  = threadIdx.x;
    const int r    = tid & 15;
    const int t    = tid >> 4;       // 0..31
    const int lane = tid & 63;

    // generation capture BEFORE any syncthreads: the following barrier's vmcnt(0) drain
    // orders this load before our arrival RMW. g_gen can only advance after *all* blocks
    // arrive, and we capture before arriving => spin race-free with relaxed ops.
    unsigned int mygen = 0u;
    if (tid == 0)
        mygen = __hip_atomic_load(&g_gen, __ATOMIC_RELAXED, __HIP_MEMORY_SCOPE_AGENT);

    for (int i = tid; i < QSTRIDE; i += 512) Bu.lh[i] = 0u;
    for (int i = tid; i < 16 * CFP_STRIDE; i += 512) A.cfp[i] = 0.f;
    for (int i = tid; i < WPADN; i += 512) {
        const float d = (float)(i - MWIN) * (1.0f / 4080.f);
        wtE[i] = (i < WTAB) ? __expf(-d * d * (1.0f / (2.0f * TAU * TAU))) : 0.f;
    }
    for (int i = tid; i < 288; i += 512) {
        cdfnp[i] = 0.f;
        onesp[i] = (i >= 13 && i < 269) ? 1.f : 0.f;
    }

    // pixel loads held in registers for the whole kernel (x read exactly once)
    const float4* xb = (const float4*)(x + (size_t)b * HW + (size_t)s * 4096);
    float4 px[2];
    px[0] = xb[tid];
    px[1] = xb[512 + tid];
    __syncthreads();

    // ---- phase 1a: fine histogram (LDS atomics, ~1 count/bin expected) ----
#pragma unroll
    for (int i = 0; i < 2; ++i) {
        const float4 v = px[i];
        int q0 = __float2int_rn(v.x * 4080.f);
        int q1 = __float2int_rn(v.y * 4080.f);
        int q2 = __float2int_rn(v.z * 4080.f);
        int q3 = __float2int_rn(v.w * 4080.f);
        q0 = min(max(q0, 0), Q - 1); q1 = min(max(q1, 0), Q - 1);
        q2 = min(max(q2, 0), Q - 1); q3 = min(max(q3, 0), Q - 1);
        atomicAdd(&Bu.lh[q0], 1u); atomicAdd(&Bu.lh[q1], 1u);
        atomicAdd(&Bu.lh[q2], 1u); atomicAdd(&Bu.lh[q3], 1u);
    }
    __syncthreads();

    // scatter fine hist phase-transposed into cfp (pads stay zero)
#pragma unroll
    for (int k = 0; k < 8; ++k) {
        const int q = k * 512 + tid;
        A.cfp[(q & 15) * CFP_STRIDE + (q >> 4) + 13] = (float)Bu.lh[q];
    }
    __syncthreads();

    // ---- phase 1b: register-blocked conv; thread (r,t) computes bins 8t..8t+7, phase r ----
    {
        float creg[34];
        const float* cbase = &A.cfp[r * CFP_STRIDE + 8 * t];
#pragma unroll
        for (int k = 0; k < 34; ++k) creg[k] = cbase[k];
        float acc[8];
#pragma unroll
        for (int uu = 0; uu < 8; ++uu) acc[uu] = 0.f;
#pragma unroll
        for (int p = 0; p < NP; ++p) {
            const float w = wtE[16 * p + r];
#pragma unroll
            for (int uu = 0; uu < 8; ++uu) acc[uu] += w * creg[uu + p];
        }
#pragma unroll
        for (int uu = 0; uu < 8; ++uu) Bu.ph[(8 * t + uu) * 17 + r] = acc[uu];
    }
    __syncthreads();

    // phase-reduce -> partial store via agent-scope atomic stores (write-through:
    // bypass L1/L2, visible device-wide once vmcnt-drained; no wbl2 fence needed)
    if (tid < N_BINS) {
        float hv = 0.f;
#pragma unroll
        for (int rr = 0; rr < 16; ++rr) hv += Bu.ph[tid * 17 + rr];
        __hip_atomic_store(&g_partT[(size_t)bid * N_BINS + tid], hv,
                           __ATOMIC_RELAXED, __HIP_MEMORY_SCOPE_AGENT);
    }

    // ---- device-wide barrier ----
    __syncthreads();   // vmcnt(0) drain: all 256 sc1 stores acked before arrival
    if (tid == 0) {
        bool master = false;
        unsigned int* c1 = &g_l1[(bid >> 3) * 16];
        const unsigned int p1 = __hip_atomic_fetch_add(c1, 1u, __ATOMIC_RELAXED,
                                                       __HIP_MEMORY_SCOPE_AGENT);
        if (p1 == 7u) {
            __hip_atomic_store(c1, 0u, __ATOMIC_RELAXED, __HIP_MEMORY_SCOPE_AGENT);
            const unsigned int p2 = __hip_atomic_fetch_add(&g_l2v, 1u, __ATOMIC_RELAXED,
                                                           __HIP_MEMORY_SCOPE_AGENT);
            if (p2 == (unsigned int)(ngrp - 1)) {
                __hip_atomic_store(&g_l2v, 0u, __ATOMIC_RELAXED, __HIP_MEMORY_SCOPE_AGENT);
                __hip_atomic_fetch_add(&g_gen, 1u, __ATOMIC_RELAXED,
                                       __HIP_MEMORY_SCOPE_AGENT);
                master = true;
            }
        }
        if (!master) {
            while (__hip_atomic_load(&g_gen, __ATOMIC_RELAXED,
                                     __HIP_MEMORY_SCOPE_AGENT) == mygen) {
                __builtin_amdgcn_s_sleep(1);
            }
        }
        // single acquire (one buffer_inv per block total, not per spin iteration)
        (void)__hip_atomic_load(&g_gen, __ATOMIC_ACQUIRE, __HIP_MEMORY_SCOPE_AGENT);
    }
    __syncthreads();

    // ---- phase 2: reduce 64x256 partials via coherent (agent atomic) loads.
    // thread owns bin = tid&255, half = tid>>8 (rows 32h..32h+31); coalesced rows.
    {
        const int bin  = tid & 255;
        const int half = tid >> 8;
        float* pb = &g_partT[(size_t)b * NPART * N_BINS + (size_t)half * 32 * N_BINS + bin];
        float hv2 = 0.f;
#pragma unroll
        for (int rr = 0; rr < 32; ++rr)
            hv2 += __hip_atomic_load(pb + (size_t)rr * N_BINS, __ATOMIC_RELAXED,
                                     __HIP_MEMORY_SCOPE_AGENT);
        Bu.p2.red2[half * 256 + bin] = hv2;
    }
    __syncthreads();

    // cross-half reduce + wave-shuffle scan over 256 bins + cdf normalization
    float val = 0.f, hv = 0.f;
    if (tid < N_BINS) {
        hv = Bu.p2.red2[tid] + Bu.p2.red2[256 + tid];
        val = hv;
#pragma unroll
        for (int d = 1; d < 64; d <<= 1) {
            const float n = __shfl_up(val, (unsigned)d, 64);
            if (lane >= d) val += n;
        }
        if (lane == 63) Bu.p2.wsum[tid >> 6] = val;
        if (tid == 0) Bu.p2.h0s = hv;
    }
    __syncthreads();
    if (tid < N_BINS) {
        float prefix = 0.f, total = 0.f;
#pragma unroll
        for (int w2 = 0; w2 < 4; ++w2) {
            const float ws = Bu.p2.wsum[w2];
            if (w2 < (tid >> 6)) prefix += ws;
            total += ws;
        }
        val += prefix;
        const float inv  = 1.0f / (total + EPS);
        const float cdf0 = Bu.p2.h0s * inv;
        cdfnp[tid + 13] = (val * inv - cdf0) / (1.0f - cdf0 + EPS);
    }
    __syncthreads();

    // ---- phase 3: output LUT (Tl overlays cfp; cfp dead since phase 1b) ----
    {
        float creg[34], oreg[34];
        const int base = 8 * t;
#pragma unroll
        for (int k = 0; k < 34; ++k) { creg[k] = cdfnp[base + k]; oreg[k] = onesp[base + k]; }
        float acc[8], sw[8];
#pragma unroll
        for (int uu = 0; uu < 8; ++uu) { acc[uu] = 0.f; sw[uu] = 0.f; }
#pragma unroll
        for (int p = 0; p < NP; ++p) {
            const float w = wtE[16 * p + r];
#pragma unroll
            for (int uu = 0; uu < 8; ++uu) {
                const int k = uu - p + 26;   // in [0,34)
                acc[uu] += w * creg[k];
                sw[uu]  += w * oreg[k];
            }
        }
#pragma unroll
        for (int uu = 0; uu < 8; ++uu)
            A.Tl[16 * (8 * t + uu) + r] = acc[uu] / (sw[uu] + EPS);
    }
    __syncthreads();

    // ---- equalize register-held pixels via LUT lerp ----
    float4* ob = (float4*)(out + (size_t)b * HW + (size_t)s * 4096);
#pragma unroll
    for (int i = 0; i < 2; ++i) {
        const float4 v = px[i];
        const float vv[4] = {v.x, v.y, v.z, v.w};
        float res[4];
#pragma unroll
        for (int k2 = 0; k2 < 4; ++k2) {
            const float u = vv[k2] * 4080.f;
            int q = (int)u;
            q = min(max(q, 0), Q - 2);
            const float frac = u - (float)q;
            const float t0 = A.Tl[q], t1 = A.Tl[q + 1];
            res[k2] = fmaf(frac, t1 - t0, t0);
        }
        ob[i * 512 + tid] = make_float4(res[0], res[1], res[2], res[3]);
    }
}

extern "C" void kernel_launch(void* const* d_in, const int* in_sizes, int n_in,
                              void* d_out, int out_size, void* d_ws, size_t ws_size,
                              hipStream_t stream) {
    const float* x = (const float*)d_in[0];
    float* out     = (float*)d_out;
    const int B    = in_sizes[0] / HW;   // = 4
    const int nblk = NPART * B;          // 256
    const int ngrp = nblk / 8;           // 32

    fused_equalize_kernel<<<dim3(NPART, B), 512, 0, stream>>>(x, out, nblk, ngrp);
}